// Round 1
// baseline (198.555 us; speedup 1.0000x reference)
//
#include <hip/hip_runtime.h>

#define NB 16        // B
#define NP 4096      // proposals/image
#define NG 512       // gt boxes/image
#define NCLS 80
#define KFG 128
#define KBG 384
#define NS 512       // sampled/image

// ---------------------------------------------------------------------------
// Kernel 1: pairwise IoU max/argmax per proposal + output zero-init.
// grid = NB*NP/256 = 256 blocks, 256 threads, 1 proposal per thread.
// ---------------------------------------------------------------------------
__global__ __launch_bounds__(256) void k_match(
    const float4* __restrict__ prop,   // [NB*NP] xyxy
    const float4* __restrict__ tgt,    // [NB*NG] xyxy
    float* __restrict__ mval,          // [NB*NP] max IoU
    int*   __restrict__ midx,          // [NB*NP] argmax gt
    float* __restrict__ out)           // [NB*NS*8 + NB*NS]
{
    __shared__ float4 tb[NG];
    __shared__ float  ta[NG];

    const int tid = threadIdx.x;
    const int b   = blockIdx.x >> 4;
    const int p   = ((blockIdx.x & 15) << 8) + tid;

    // ---- init output: boxes region -> 0, cls region -> -1 ----
    // 65536 threads total; boxes region is exactly NB*NS*8 = 65536 floats.
    const int gid = blockIdx.x * 256 + tid;
    out[gid] = 0.0f;
    if (gid < NB * NS) out[NB * NS * 8 + gid] = -1.0f;

    // ---- stage gt boxes + areas ----
    for (int i = tid; i < NG; i += 256) {
        float4 t = tgt[b * NG + i];
        tb[i] = t;
        ta[i] = __fmul_rn(__fsub_rn(t.z, t.x), __fsub_rn(t.w, t.y));
    }
    __syncthreads();

    const float4 pb = prop[b * NP + p];
    const float ap = __fmul_rn(__fsub_rn(pb.z, pb.x), __fsub_rn(pb.w, pb.y));

    float best = -1.0f;
    int   bi   = 0;
    #pragma unroll 4
    for (int g = 0; g < NG; ++g) {
        const float4 t = tb[g];
        const float ltx = fmaxf(t.x, pb.x);
        const float lty = fmaxf(t.y, pb.y);
        const float rbx = fminf(t.z, pb.z);
        const float rby = fminf(t.w, pb.w);
        const float w = fmaxf(__fsub_rn(rbx, ltx), 0.0f);
        const float h = fmaxf(__fsub_rn(rby, lty), 0.0f);
        const float inter = __fmul_rn(w, h);
        const float uni   = __fsub_rn(__fadd_rn(ta[g], ap), inter);
        const float iou   = (inter > 0.0f)
                              ? __fdiv_rn(inter, fmaxf(uni, 1e-8f))
                              : 0.0f;
        if (iou > best) { best = iou; bi = g; }   // first-occurrence argmax
    }
    mval[b * NP + p] = best;
    midx[b * NP + p] = bi;
}

// ---------------------------------------------------------------------------
// Kernel 2: exact stable rank within {fg, bg} pools by brute-force count,
// then scatter the top-KFG fg / top-KBG bg into the output slots.
// grid = NB * (NP/64) = 1024 blocks, 256 threads; 4 lanes per proposal.
// ---------------------------------------------------------------------------
__global__ __launch_bounds__(256) void k_select(
    const float4* __restrict__ prop,
    const float4* __restrict__ tgt,
    const int*   __restrict__ gtc,     // [NB*NG]
    const float* __restrict__ pri,     // [NB*NP]
    const float* __restrict__ mval,
    const int*   __restrict__ midx,
    float* __restrict__ out)
{
    __shared__ float2 pk[NP];          // {priority, fg?1:0} — 32 KiB

    const int tid = threadIdx.x;
    const int b   = blockIdx.x >> 6;   // 64 blocks per image
    const int j   = blockIdx.x & 63;

    for (int i = tid; i < NP; i += 256) {
        float v = pri[b * NP + i];
        float f = (mval[b * NP + i] >= 0.5f) ? 1.0f : 0.0f;
        pk[i] = make_float2(v, f);
    }
    __syncthreads();

    const int q  = tid >> 2;           // proposal sub-index 0..63
    const int s4 = tid & 3;            // scanner 0..3
    const int p  = j * 64 + q;

    const float2 me   = pk[p];
    const float mypri = me.x;
    const float myfg  = me.y;

    int rank = 0;
    const int base = s4 * 1024;
    #pragma unroll 4
    for (int k = 0; k < 1024; ++k) {
        const int i = base + ((k + s4) & 1023);   // s4-rotation: distinct banks
        const float2 o = pk[i];
        const bool same  = (o.y == myfg);
        const bool ahead = same && ((o.x > mypri) | ((o.x == mypri) & (i < p)));
        rank += ahead ? 1 : 0;
    }
    rank += __shfl_xor(rank, 1);
    rank += __shfl_xor(rank, 2);

    if (s4 == 0) {
        const bool fg  = (myfg != 0.0f);
        const int  cap = fg ? KFG : KBG;
        if (rank < cap) {
            const int slot = b * NS + (fg ? rank : (KFG + rank));
            const int mi   = midx[b * NP + p];
            const float4 pb4 = prop[b * NP + p];
            const float4 tb4 = tgt[b * NG + mi];
            const float cls = fg ? (float)gtc[b * NG + mi] : (float)NCLS;
            float4* orow = (float4*)(out + (size_t)slot * 8);
            orow[0] = pb4;
            orow[1] = tb4;
            out[NB * NS * 8 + slot] = cls;
        }
    }
}

extern "C" void kernel_launch(void* const* d_in, const int* in_sizes, int n_in,
                              void* d_out, int out_size, void* d_ws, size_t ws_size,
                              hipStream_t stream) {
    const float4* prop = (const float4*)d_in[0];   // [16,4096,4] f32
    const float4* tgt  = (const float4*)d_in[1];   // [16,512,4]  f32
    const int*    gtc  = (const int*)  d_in[2];    // [16,512]    i32
    const float*  pri  = (const float*)d_in[3];    // [16,4096]   f32
    float* out = (float*)d_out;

    float* mval = (float*)d_ws;                    // NB*NP floats
    int*   midx = (int*)((char*)d_ws + (size_t)NB * NP * sizeof(float));

    k_match<<<NB * NP / 256, 256, 0, stream>>>(prop, tgt, mval, midx, out);
    k_select<<<NB * (NP / 64), 256, 0, stream>>>(prop, tgt, gtc, pri, mval, midx, out);
}

// Round 2
// 95.749 us; speedup vs baseline: 2.0737x; 2.0737x over previous
//
#include <hip/hip_runtime.h>
#include <stdint.h>

#define NB 16        // images
#define NP 4096      // proposals/image
#define NG 512       // gt/image
#define NCH 4        // gt chunks for k_match
#define GC  (NG/NCH) // 128
#define NCLS 80
#define KFG 128
#define KBG 384
#define NS 512
#define OUT_BOX (NB*NS*8)   // 65536 floats
#define OUT_CLS (NB*NS)     // 8192 floats
#define NBNP (NB*NP)

typedef unsigned long long u64;

// ---------------------------------------------------------------------------
// Kernel 1: partial IoU max/argmax over a 128-gt chunk + output init.
// grid = NB*16*NCH = 1024 blocks x 256 thr (4 waves/SIMD -> latency hidden).
// Packed partial: (iou_bits << 16) | (511 - g_global).  Plain u64 max over
// chunks == max IoU with first-occurrence (smallest g) tie-break.
// ---------------------------------------------------------------------------
__global__ __launch_bounds__(256) void k_match(
    const float4* __restrict__ prop,
    const float4* __restrict__ tgt,
    u64* __restrict__ pm,              // [NCH][NB*NP]
    float* __restrict__ out)
{
    __shared__ float4 tb[GC];
    __shared__ float  ta[GC];

    const int tid  = threadIdx.x;
    const int bx   = blockIdx.x;
    const int c    = bx & 3;
    const int pblk = (bx >> 2) & 15;
    const int b    = bx >> 6;

    // ---- init output (poisoned once by harness): boxes->0, cls->-1 ----
    const int gid = bx * 256 + tid;
    if (gid < OUT_BOX) out[gid] = 0.0f;
    if (gid < OUT_CLS) out[OUT_BOX + gid] = -1.0f;

    for (int i = tid; i < GC; i += 256) {
        float4 t = tgt[b * NG + c * GC + i];
        tb[i] = t;
        ta[i] = __fmul_rn(__fsub_rn(t.z, t.x), __fsub_rn(t.w, t.y));
    }
    __syncthreads();

    const int p = pblk * 256 + tid;
    const float4 pb = prop[b * NP + p];
    const float ap = __fmul_rn(__fsub_rn(pb.z, pb.x), __fsub_rn(pb.w, pb.y));

    float best = -1.0f;
    int   bi   = 0;
    #pragma unroll 4
    for (int g = 0; g < GC; ++g) {
        const float4 t = tb[g];
        const float ltx = fmaxf(t.x, pb.x);
        const float lty = fmaxf(t.y, pb.y);
        const float rbx = fminf(t.z, pb.z);
        const float rby = fminf(t.w, pb.w);
        const float w = fmaxf(__fsub_rn(rbx, ltx), 0.0f);
        const float h = fmaxf(__fsub_rn(rby, lty), 0.0f);
        const float inter = __fmul_rn(w, h);
        const float uni   = __fsub_rn(__fadd_rn(ta[g], ap), inter);
        const float iou   = (inter > 0.0f)
                              ? __fdiv_rn(inter, fmaxf(uni, 1e-8f))
                              : 0.0f;
        if (iou > best) { best = iou; bi = g; }   // first-occurrence in chunk
    }
    const int gg = c * GC + bi;                    // global gt index
    const unsigned vb = __float_as_uint(best);     // best>=0 -> bits ordered
    pm[c * NBNP + b * NP + p] = ((u64)vb << 16) | (u64)(NG - 1 - gg);
}

// ---------------------------------------------------------------------------
// Kernel 2: combine partials, build 45-bit sort keys, per-image bitonic sort
// (descending) in LDS, then scatter top-KFG fg / top-KBG bg directly by
// sorted position.  grid = NB blocks x 1024 thr, 4 elements/thread.
// key = (fg<<44) | (pri_bits<<12) | (4095 - p)   -> stable lax.top_k order.
// ---------------------------------------------------------------------------
__global__ __launch_bounds__(1024) void k_sortsel(
    const float4* __restrict__ prop,
    const float4* __restrict__ tgt,
    const int*   __restrict__ gtc,
    const float* __restrict__ pri,
    const u64*   __restrict__ pm,
    float* __restrict__ out)
{
    __shared__ u64 skey[NP];     // 32 KiB
    __shared__ int smidx[NP];    // 16 KiB
    __shared__ int s_fg;

    const int tid = threadIdx.x;
    const int b   = blockIdx.x;

    if (tid == 0) s_fg = 0;
    __syncthreads();

    int cnt = 0;
    #pragma unroll
    for (int t = 0; t < 4; ++t) {
        const int p = tid + t * 1024;
        const int idx = b * NP + p;
        u64 m = pm[idx];
        u64 m1 = pm[1 * NBNP + idx]; if (m1 > m) m = m1;
        u64 m2 = pm[2 * NBNP + idx]; if (m2 > m) m = m2;
        u64 m3 = pm[3 * NBNP + idx]; if (m3 > m) m = m3;
        const float best = __uint_as_float((unsigned)(m >> 16));
        const int   gg   = (NG - 1) - (int)(m & 0xFFFF);
        const bool  fg   = (best >= 0.5f);
        const unsigned pbits = __float_as_uint(pri[idx]);   // pri in [0,1): ordered bits
        skey[p]  = ((u64)(fg ? 1u : 0u) << 44) | ((u64)pbits << 12) | (u64)(NP - 1 - p);
        smidx[p] = gg;
        cnt += fg ? 1 : 0;
    }
    atomicAdd(&s_fg, cnt);
    __syncthreads();

    // ---- bitonic sort, descending ----
    for (int k = 2; k <= NP; k <<= 1) {
        for (int j = k >> 1; j > 0; j >>= 1) {
            #pragma unroll
            for (int t = 0; t < 4; ++t) {
                const int i = tid + t * 1024;
                const int l = i ^ j;
                if (l > i) {
                    const u64 x = skey[i];
                    const u64 y = skey[l];
                    const bool up = ((i & k) == 0);
                    const bool sw = up ? (x < y) : (x > y);
                    if (sw) { skey[i] = y; skey[l] = x; }
                }
            }
            __syncthreads();
        }
    }

    const int fgc = s_fg;
    #pragma unroll
    for (int t = 0; t < 4; ++t) {
        const int pos = tid + t * 1024;
        const u64 kk = skey[pos];
        const int cat = (int)(kk >> 44);
        const int p   = (NP - 1) - (int)(kk & 0xFFF);
        int slot = -1;
        if (cat) {                       // fg occupy positions [0, fgc)
            if (pos < KFG) slot = pos;
        } else {
            const int r = pos - fgc;     // rank within bg
            if (r < KBG) slot = KFG + r;
        }
        if (slot >= 0) {
            slot += b * NS;
            const float4 pb4 = prop[b * NP + p];
            const int    mi  = smidx[p];
            const float4 tb4 = tgt[b * NG + mi];
            const float  cls = cat ? (float)gtc[b * NG + mi] : (float)NCLS;
            float4* orow = (float4*)(out + (size_t)slot * 8);
            orow[0] = pb4;
            orow[1] = tb4;
            out[OUT_BOX + slot] = cls;
        }
    }
}

extern "C" void kernel_launch(void* const* d_in, const int* in_sizes, int n_in,
                              void* d_out, int out_size, void* d_ws, size_t ws_size,
                              hipStream_t stream) {
    const float4* prop = (const float4*)d_in[0];   // [16,4096,4] f32
    const float4* tgt  = (const float4*)d_in[1];   // [16,512,4]  f32
    const int*    gtc  = (const int*)  d_in[2];    // [16,512]    i32
    const float*  pri  = (const float*)d_in[3];    // [16,4096]   f32
    float* out = (float*)d_out;

    u64* pm = (u64*)d_ws;                          // NCH * NB*NP * 8B = 2 MiB

    k_match<<<NB * 16 * NCH, 256, 0, stream>>>(prop, tgt, pm, out);
    k_sortsel<<<NB, 1024, 0, stream>>>(prop, tgt, gtc, pri, pm, out);
}

// Round 4
// 49.685 us; speedup vs baseline: 3.9963x; 1.9271x over previous
//
#include <hip/hip_runtime.h>
#include <stdint.h>

#define NB 16        // images
#define NP 4096      // proposals/image
#define NG 512       // gt/image
#define NCH 8        // gt chunks for k_match
#define GC  (NG/NCH) // 64
#define NCLS 80
#define KFG 128
#define KBG 384
#define NS 512
#define OUT_BOX (NB*NS*8)   // 65536 floats
#define OUT_CLS (NB*NS)     // 8192 floats
#define NBNP (NB*NP)
#define NBK 256             // priority buckets per category

typedef unsigned long long u64;

// ---------------------------------------------------------------------------
// Kernel 1: partial IoU max/argmax over a 64-gt chunk, combined across chunks
// via atomicMax on packed u64 (iou_bits<<16 | (511-g)) -> exact first-
// occurrence argmax.  grid = NB*16*NCH = 2048 blocks (8 waves/SIMD).
// Division filter: skip fdiv when (double)inter <= (double)best*(double)uni.
// f32*f32 is exact in f64, and RN is monotone: inter/uni <= best implies
// RN(inter/uni) <= best -> no update possible -> skip is safe.
// ---------------------------------------------------------------------------
__global__ __launch_bounds__(256) void k_match(
    const float4* __restrict__ prop,
    const float4* __restrict__ tgt,
    u64* __restrict__ pm)              // [NB*NP], pre-zeroed
{
    __shared__ float4 tb[GC];
    __shared__ float  ta[GC];

    const int tid  = threadIdx.x;
    const int bx   = blockIdx.x;
    const int c    = bx & (NCH - 1);
    const int pblk = (bx >> 3) & 15;
    const int b    = bx >> 7;

    if (tid < GC) {
        float4 t = tgt[b * NG + c * GC + tid];
        tb[tid] = t;
        ta[tid] = __fmul_rn(__fsub_rn(t.z, t.x), __fsub_rn(t.w, t.y));
    }
    __syncthreads();

    const int p = pblk * 256 + tid;
    const float4 pb = prop[b * NP + p];
    const float ap = __fmul_rn(__fsub_rn(pb.z, pb.x), __fsub_rn(pb.w, pb.y));

    float best = -1.0f;
    int   bi   = 0;
    #pragma unroll 4
    for (int g = 0; g < GC; ++g) {
        const float4 t = tb[g];
        const float ltx = fmaxf(t.x, pb.x);
        const float lty = fmaxf(t.y, pb.y);
        const float rbx = fminf(t.z, pb.z);
        const float rby = fminf(t.w, pb.w);
        const float w = fmaxf(__fsub_rn(rbx, ltx), 0.0f);
        const float h = fmaxf(__fsub_rn(rby, lty), 0.0f);
        const float inter = __fmul_rn(w, h);
        const float uni   = __fsub_rn(__fadd_rn(ta[g], ap), inter);
        if ((double)inter > (double)best * (double)uni) {   // conservative skip
            const float iou = (inter > 0.0f)
                                ? __fdiv_rn(inter, fmaxf(uni, 1e-8f))
                                : 0.0f;
            if (iou > best) { best = iou; bi = g; }  // first-occurrence
        }
    }
    const int gg = c * GC + bi;
    const u64 v = ((u64)__float_as_uint(best) << 16) | (u64)(NG - 1 - gg);
    atomicMax(&pm[b * NP + p], v);
}

// ---------------------------------------------------------------------------
// Kernel 2: exact stable rank via 256-bucket counting sort per category.
// rank = (descending-bucket exclusive prefix within category)
//      + (# same-bucket keys strictly greater).  key=(pribits<<12)|(4095-p).
// grid = NB blocks x 1024 thr.  Also inits this image's output slice.
// ---------------------------------------------------------------------------
__global__ __launch_bounds__(1024) void k_select(
    const float4* __restrict__ prop,
    const float4* __restrict__ tgt,
    const int*   __restrict__ gtc,
    const float* __restrict__ pri,
    const u64*   __restrict__ pm,
    float* __restrict__ out)
{
    __shared__ int cnt[2 * NBK];       // counts per (cat,bucket)
    __shared__ int bsa[2 * NBK];       // global exclusive start (scatter addr)
    __shared__ int cur[2 * NBK];       // scatter cursor
    __shared__ int sA[2 * NBK], sB[2 * NBK];
    __shared__ int s_tot0;
    __shared__ u64 gkeys[NP];          // 32 KiB grouped keys

    const int tid = threadIdx.x;
    const int b   = blockIdx.x;

    // ---- init this image's output slice (harness poisons once) ----
    float* oimg = out + (size_t)b * NS * 8;
    #pragma unroll
    for (int i = tid; i < NS * 8; i += 1024) oimg[i] = 0.0f;
    if (tid < NS) out[OUT_BOX + b * NS + tid] = -1.0f;

    if (tid < 2 * NBK) cnt[tid] = 0;
    __syncthreads();

    int mcat[4], mgrp[4], mmid[4];
    u64 mkey[4];
    #pragma unroll
    for (int t = 0; t < 4; ++t) {
        const int p = tid + t * 1024;
        const u64 m = pm[b * NP + p];
        const float best = __uint_as_float((unsigned)(m >> 16));
        mmid[t] = (NG - 1) - (int)(m & 0xFFFF);
        const int cat = (best >= 0.5f) ? 1 : 0;        // fg = 1
        const float v = pri[b * NP + p];
        int bkt = (int)(v * 256.0f); if (bkt > 255) bkt = 255;
        mcat[t] = cat;
        mgrp[t] = cat * NBK + bkt;
        mkey[t] = ((u64)__float_as_uint(v) << 12) | (u64)(NP - 1 - p);
        atomicAdd(&cnt[mgrp[t]], 1);
    }
    __syncthreads();

    // scan order s: cat segment (bg first), buckets DESCENDING within segment
    // grp(s) = (s & 256) | (255 - (s & 255))
    if (tid < 2 * NBK) sA[tid] = cnt[(tid & 256) | (255 - (tid & 255))];
    __syncthreads();

    int* pa = sA; int* pb2 = sB;
    for (int d = 1; d < 2 * NBK; d <<= 1) {            // 9 steps, inclusive scan
        if (tid < 2 * NBK) pb2[tid] = pa[tid] + ((tid >= d) ? pa[tid - d] : 0);
        __syncthreads();
        int* tmp = pa; pa = pb2; pb2 = tmp;
    }
    if (tid == 0) s_tot0 = pa[NBK - 1];                // total bg count
    if (tid < 2 * NBK) {
        const int grp = (tid & 256) | (255 - (tid & 255));
        const int excl = pa[tid] - cnt[grp];
        bsa[grp] = excl;
        cur[grp] = excl;
    }
    __syncthreads();

    // ---- counting-scatter keys into bucket groups ----
    #pragma unroll
    for (int t = 0; t < 4; ++t) {
        const int off = atomicAdd(&cur[mgrp[t]], 1);
        gkeys[off] = mkey[t];
    }
    __syncthreads();

    const int tot0 = s_tot0;
    #pragma unroll
    for (int t = 0; t < 4; ++t) {
        const int grp = mgrp[t];
        const int gs  = bsa[grp];
        const int gc  = cnt[grp];
        const u64 mine = mkey[t];
        int ahead = 0;
        for (int i = gs; i < gs + gc; ++i)
            ahead += (gkeys[i] > mine) ? 1 : 0;
        const int cat  = mcat[t];
        const int rank = (gs - (cat ? tot0 : 0)) + ahead;   // rank within category
        const int cap  = cat ? KFG : KBG;
        if (rank < cap) {
            const int p    = tid + t * 1024;
            const int slot = b * NS + (cat ? rank : KFG + rank);
            const float4 pb4 = prop[b * NP + p];
            const int    mi  = mmid[t];
            const float4 tb4 = tgt[b * NG + mi];
            float4* orow = (float4*)(out + (size_t)slot * 8);
            orow[0] = pb4;
            orow[1] = tb4;
            out[OUT_BOX + slot] = cat ? (float)gtc[b * NG + mi] : (float)NCLS;
        }
    }
}

extern "C" void kernel_launch(void* const* d_in, const int* in_sizes, int n_in,
                              void* d_out, int out_size, void* d_ws, size_t ws_size,
                              hipStream_t stream) {
    const float4* prop = (const float4*)d_in[0];   // [16,4096,4] f32
    const float4* tgt  = (const float4*)d_in[1];   // [16,512,4]  f32
    const int*    gtc  = (const int*)  d_in[2];    // [16,512]    i32
    const float*  pri  = (const float*)d_in[3];    // [16,4096]   f32
    float* out = (float*)d_out;

    u64* pm = (u64*)d_ws;                          // NB*NP * 8B = 512 KiB
    (void)hipMemsetAsync(pm, 0, (size_t)NBNP * sizeof(u64), stream);

    k_match<<<NB * 16 * NCH, 256, 0, stream>>>(prop, tgt, pm);
    k_select<<<NB, 1024, 0, stream>>>(prop, tgt, gtc, pri, pm, out);
}

// Round 5
// 48.270 us; speedup vs baseline: 4.1134x; 1.0293x over previous
//
#include <hip/hip_runtime.h>
#include <stdint.h>

#define NB 16        // images
#define NP 4096      // proposals/image
#define NG 512       // gt/image
#define NCH 8        // gt chunks for k_match
#define GC  (NG/NCH) // 64
#define NCLS 80
#define KFG 128
#define KBG 384
#define NS 512
#define OUT_BOX (NB*NS*8)   // 65536 floats
#define OUT_CLS (NB*NS)     // 8192 floats
#define NBNP (NB*NP)
#define NBK 256             // priority buckets per category

typedef unsigned long long u64;

// ---------------------------------------------------------------------------
// Kernel 1: partial IoU max/argmax over a 64-gt chunk, written UNCONDITIONALLY
// to pm[c][b*NP+p] (no atomics -> no pre-zeroing -> no memset in the graph).
// Packed (iou_bits<<16 | (511-g)); u64 max across chunks == first-occurrence
// argmax.  grid = NB*16*NCH = 2048 blocks (8 waves/SIMD).
// Division filter: skip fdiv when (double)inter <= (double)best*(double)uni.
// f32*f32 is exact in f64, and RN is monotone: inter/uni <= best implies
// RN(inter/uni) <= best -> no update possible -> skip is safe.
// ---------------------------------------------------------------------------
__global__ __launch_bounds__(256) void k_match(
    const float4* __restrict__ prop,
    const float4* __restrict__ tgt,
    u64* __restrict__ pm)              // [NCH][NB*NP]
{
    __shared__ float4 tb[GC];
    __shared__ float  ta[GC];

    const int tid  = threadIdx.x;
    const int bx   = blockIdx.x;
    const int c    = bx & (NCH - 1);
    const int pblk = (bx >> 3) & 15;
    const int b    = bx >> 7;

    if (tid < GC) {
        float4 t = tgt[b * NG + c * GC + tid];
        tb[tid] = t;
        ta[tid] = __fmul_rn(__fsub_rn(t.z, t.x), __fsub_rn(t.w, t.y));
    }
    __syncthreads();

    const int p = pblk * 256 + tid;
    const float4 pb = prop[b * NP + p];
    const float ap = __fmul_rn(__fsub_rn(pb.z, pb.x), __fsub_rn(pb.w, pb.y));

    float best = -1.0f;
    int   bi   = 0;
    #pragma unroll 4
    for (int g = 0; g < GC; ++g) {
        const float4 t = tb[g];
        const float ltx = fmaxf(t.x, pb.x);
        const float lty = fmaxf(t.y, pb.y);
        const float rbx = fminf(t.z, pb.z);
        const float rby = fminf(t.w, pb.w);
        const float w = fmaxf(__fsub_rn(rbx, ltx), 0.0f);
        const float h = fmaxf(__fsub_rn(rby, lty), 0.0f);
        const float inter = __fmul_rn(w, h);
        const float uni   = __fsub_rn(__fadd_rn(ta[g], ap), inter);
        if ((double)inter > (double)best * (double)uni) {   // conservative skip
            const float iou = (inter > 0.0f)
                                ? __fdiv_rn(inter, fmaxf(uni, 1e-8f))
                                : 0.0f;
            if (iou > best) { best = iou; bi = g; }  // first-occurrence
        }
    }
    const int gg = c * GC + bi;
    pm[c * NBNP + b * NP + p] =
        ((u64)__float_as_uint(best) << 16) | (u64)(NG - 1 - gg);
}

// ---------------------------------------------------------------------------
// Kernel 2: combine 8 partials, then exact stable rank via 256-bucket
// counting sort per category.
// rank = (descending-bucket exclusive prefix within category)
//      + (# same-bucket keys strictly greater).  key=(pribits<<12)|(4095-p).
// grid = NB blocks x 1024 thr.  Also inits this image's output slice.
// ---------------------------------------------------------------------------
__global__ __launch_bounds__(1024) void k_select(
    const float4* __restrict__ prop,
    const float4* __restrict__ tgt,
    const int*   __restrict__ gtc,
    const float* __restrict__ pri,
    const u64*   __restrict__ pm,
    float* __restrict__ out)
{
    __shared__ int cnt[2 * NBK];       // counts per (cat,bucket)
    __shared__ int bsa[2 * NBK];       // global exclusive start (scatter addr)
    __shared__ int cur[2 * NBK];       // scatter cursor
    __shared__ int sA[2 * NBK], sB[2 * NBK];
    __shared__ int s_tot0;
    __shared__ u64 gkeys[NP];          // 32 KiB grouped keys

    const int tid = threadIdx.x;
    const int b   = blockIdx.x;

    // ---- init this image's output slice (harness poisons once) ----
    float* oimg = out + (size_t)b * NS * 8;
    #pragma unroll
    for (int i = tid; i < NS * 8; i += 1024) oimg[i] = 0.0f;
    if (tid < NS) out[OUT_BOX + b * NS + tid] = -1.0f;

    if (tid < 2 * NBK) cnt[tid] = 0;
    __syncthreads();

    int mcat[4], mgrp[4], mmid[4];
    u64 mkey[4];
    #pragma unroll
    for (int t = 0; t < 4; ++t) {
        const int p = tid + t * 1024;
        const int idx = b * NP + p;
        u64 m = pm[idx];
        #pragma unroll
        for (int c = 1; c < NCH; ++c) {
            const u64 mc = pm[c * NBNP + idx];
            if (mc > m) m = mc;
        }
        const float best = __uint_as_float((unsigned)(m >> 16));
        mmid[t] = (NG - 1) - (int)(m & 0xFFFF);
        const int cat = (best >= 0.5f) ? 1 : 0;        // fg = 1
        const float v = pri[idx];
        int bkt = (int)(v * 256.0f); if (bkt > 255) bkt = 255;
        mcat[t] = cat;
        mgrp[t] = cat * NBK + bkt;
        mkey[t] = ((u64)__float_as_uint(v) << 12) | (u64)(NP - 1 - p);
        atomicAdd(&cnt[mgrp[t]], 1);
    }
    __syncthreads();

    // scan order s: cat segment (bg first), buckets DESCENDING within segment
    // grp(s) = (s & 256) | (255 - (s & 255))
    if (tid < 2 * NBK) sA[tid] = cnt[(tid & 256) | (255 - (tid & 255))];
    __syncthreads();

    int* pa = sA; int* pb2 = sB;
    for (int d = 1; d < 2 * NBK; d <<= 1) {            // 9 steps, inclusive scan
        if (tid < 2 * NBK) pb2[tid] = pa[tid] + ((tid >= d) ? pa[tid - d] : 0);
        __syncthreads();
        int* tmp = pa; pa = pb2; pb2 = tmp;
    }
    if (tid == 0) s_tot0 = pa[NBK - 1];                // total bg count
    if (tid < 2 * NBK) {
        const int grp = (tid & 256) | (255 - (tid & 255));
        const int excl = pa[tid] - cnt[grp];
        bsa[grp] = excl;
        cur[grp] = excl;
    }
    __syncthreads();

    // ---- counting-scatter keys into bucket groups ----
    #pragma unroll
    for (int t = 0; t < 4; ++t) {
        const int off = atomicAdd(&cur[mgrp[t]], 1);
        gkeys[off] = mkey[t];
    }
    __syncthreads();

    const int tot0 = s_tot0;
    #pragma unroll
    for (int t = 0; t < 4; ++t) {
        const int grp = mgrp[t];
        const int gs  = bsa[grp];
        const int gc  = cnt[grp];
        const u64 mine = mkey[t];
        int ahead = 0;
        for (int i = gs; i < gs + gc; ++i)
            ahead += (gkeys[i] > mine) ? 1 : 0;
        const int cat  = mcat[t];
        const int rank = (gs - (cat ? tot0 : 0)) + ahead;   // rank within category
        const int cap  = cat ? KFG : KBG;
        if (rank < cap) {
            const int p    = tid + t * 1024;
            const int slot = b * NS + (cat ? rank : KFG + rank);
            const float4 pb4 = prop[b * NP + p];
            const int    mi  = mmid[t];
            const float4 tb4 = tgt[b * NG + mi];
            float4* orow = (float4*)(out + (size_t)slot * 8);
            orow[0] = pb4;
            orow[1] = tb4;
            out[OUT_BOX + slot] = cat ? (float)gtc[b * NG + mi] : (float)NCLS;
        }
    }
}

extern "C" void kernel_launch(void* const* d_in, const int* in_sizes, int n_in,
                              void* d_out, int out_size, void* d_ws, size_t ws_size,
                              hipStream_t stream) {
    const float4* prop = (const float4*)d_in[0];   // [16,4096,4] f32
    const float4* tgt  = (const float4*)d_in[1];   // [16,512,4]  f32
    const int*    gtc  = (const int*)  d_in[2];    // [16,512]    i32
    const float*  pri  = (const float*)d_in[3];    // [16,4096]   f32
    float* out = (float*)d_out;

    u64* pm = (u64*)d_ws;                          // NCH * NB*NP * 8B = 4 MiB

    k_match<<<NB * 16 * NCH, 256, 0, stream>>>(prop, tgt, pm);
    k_select<<<NB, 1024, 0, stream>>>(prop, tgt, gtc, pri, pm, out);
}

// Round 6
// 46.879 us; speedup vs baseline: 4.2354x; 1.0297x over previous
//
#include <hip/hip_runtime.h>
#include <stdint.h>

#define NB 16        // images
#define NP 4096      // proposals/image
#define NG 512       // gt/image
#define NCH 8        // gt chunks for k_match
#define GC  (NG/NCH) // 64
#define NCLS 80
#define KFG 128
#define KBG 384
#define NS 512
#define OUT_BOX (NB*NS*8)   // 65536 floats
#define OUT_CLS (NB*NS)     // 8192 floats
#define NBNP (NB*NP)
#define NBK 256             // priority buckets per category
#define NGRP (2*NBK)        // 512 (cat,bucket) groups
#define RBLK 16             // rank blocks per image
#define CHK (NP/RBLK)       // 256 proposals ranked per block

typedef unsigned long long u64;

// ---------------------------------------------------------------------------
// Kernel 1: partial IoU max/argmax over a 64-gt chunk, written UNCONDITIONALLY
// to pm[c][b*NP+p].  Packed (iou_bits<<16 | (511-g)); u64 max across chunks ==
// first-occurrence argmax.  grid = NB*16*NCH = 2048 blocks (8 waves/SIMD).
// Also inits the output (boxes->0, cls->-1); harness poisons only once.
// f32 division filter: skip fdiv when inter <= s, s = fmaf(t,-2^-23,t),
// t = RN(best*uni).  Proof: s <= best*uni*(1+2^-24)^2*(1-2^-23) < best*uni,
// so skip => quotient <= best => RN(quotient) <= best => no update possible.
// ---------------------------------------------------------------------------
__global__ __launch_bounds__(256) void k_match(
    const float4* __restrict__ prop,
    const float4* __restrict__ tgt,
    u64* __restrict__ pm,              // [NCH][NB*NP]
    float* __restrict__ out)
{
    __shared__ float4 tb[GC];
    __shared__ float  ta[GC];

    const int tid  = threadIdx.x;
    const int bx   = blockIdx.x;
    const int c    = bx & (NCH - 1);
    const int pblk = (bx >> 3) & 15;
    const int b    = bx >> 7;

    // ---- output init (524288 threads total) ----
    const int gid = bx * 256 + tid;
    if (gid < OUT_BOX) out[gid] = 0.0f;
    if (gid < OUT_CLS) out[OUT_BOX + gid] = -1.0f;

    if (tid < GC) {
        float4 t = tgt[b * NG + c * GC + tid];
        tb[tid] = t;
        ta[tid] = __fmul_rn(__fsub_rn(t.z, t.x), __fsub_rn(t.w, t.y));
    }
    __syncthreads();

    const int p = pblk * 256 + tid;
    const float4 pb = prop[b * NP + p];
    const float ap = __fmul_rn(__fsub_rn(pb.z, pb.x), __fsub_rn(pb.w, pb.y));

    float best = -1.0f;
    int   bi   = 0;
    #pragma unroll 4
    for (int g = 0; g < GC; ++g) {
        const float4 t = tb[g];
        const float ltx = fmaxf(t.x, pb.x);
        const float lty = fmaxf(t.y, pb.y);
        const float rbx = fminf(t.z, pb.z);
        const float rby = fminf(t.w, pb.w);
        const float w = fmaxf(__fsub_rn(rbx, ltx), 0.0f);
        const float h = fmaxf(__fsub_rn(rby, lty), 0.0f);
        const float inter = __fmul_rn(w, h);
        const float uni   = __fsub_rn(__fadd_rn(ta[g], ap), inter);
        const float tt = __fmul_rn(best, uni);
        const float ss = fmaf(tt, -0x1p-23f, tt);        // conservative bound
        if (inter > ss) {
            const float iou = (inter > 0.0f)
                                ? __fdiv_rn(inter, fmaxf(uni, 1e-8f))
                                : 0.0f;
            if (iou > best) { best = iou; bi = g; }      // first-occurrence
        }
    }
    const int gg = c * GC + bi;
    pm[c * NBNP + b * NP + p] =
        ((u64)__float_as_uint(best) << 16) | (u64)(NG - 1 - gg);
}

// ---------------------------------------------------------------------------
// Kernel 2: exact stable rank via 256-bucket counting sort per category,
// REDUNDANTLY staged per block so all 256 CUs work.
// grid = NB*RBLK = 256 blocks x 512 thr; each block rebuilds the full
// per-image grouped-key LDS image (stage 8/thread, hist, 9-step scan,
// scatter), then ranks + scatters only its 256-proposal chunk.
// rank = (descending-bucket exclusive prefix within category)
//      + (# same-bucket keys strictly greater).  key=(pribits<<12)|(4095-p).
// ---------------------------------------------------------------------------
__global__ __launch_bounds__(512) void k_rank(
    const float4* __restrict__ prop,
    const float4* __restrict__ tgt,
    const int*   __restrict__ gtc,
    const float* __restrict__ pri,
    const u64*   __restrict__ pm,
    float* __restrict__ out)
{
    __shared__ u64 gkeys[NP];          // 32 KiB grouped keys
    __shared__ int cnt[NGRP];          // counts per (cat,bucket)
    __shared__ int bsa[NGRP];          // exclusive start in grouped order
    __shared__ int cur[NGRP];          // scatter cursor
    __shared__ int sA[NGRP], sB[NGRP];
    __shared__ int s_tot0;

    const int tid = threadIdx.x;       // 0..511
    const int b   = blockIdx.x >> 4;
    const int j   = blockIdx.x & (RBLK - 1);

    cnt[tid] = 0;
    __syncthreads();

    // ---- stage all 4096 proposals' (key, grp): 8 per thread ----
    u64 skey[8]; short sgrp[8];
    #pragma unroll
    for (int t = 0; t < 8; ++t) {
        const int p = tid + t * 512;
        const int idx = b * NP + p;
        u64 m = pm[idx];
        #pragma unroll
        for (int c = 1; c < NCH; ++c) {
            const u64 mc = pm[c * NBNP + idx];
            if (mc > m) m = mc;
        }
        const float best = __uint_as_float((unsigned)(m >> 16));
        const int cat = (best >= 0.5f) ? 1 : 0;
        const float v = pri[idx];
        int bkt = (int)(v * 256.0f); if (bkt > 255) bkt = 255;
        const int grp = cat * NBK + bkt;
        skey[t] = ((u64)__float_as_uint(v) << 12) | (u64)(NP - 1 - p);
        sgrp[t] = (short)grp;
        atomicAdd(&cnt[grp], 1);
    }
    __syncthreads();

    // ---- scan order s: bg segment first, buckets DESCENDING within segment
    // grp(s) = (s & 256) | (255 - (s & 255))
    sA[tid] = cnt[(tid & 256) | (255 - (tid & 255))];
    __syncthreads();

    int* pa = sA; int* pb2 = sB;
    for (int d = 1; d < NGRP; d <<= 1) {               // 9 steps, inclusive scan
        pb2[tid] = pa[tid] + ((tid >= d) ? pa[tid - d] : 0);
        __syncthreads();
        int* tmp = pa; pa = pb2; pb2 = tmp;
    }
    if (tid == 0) s_tot0 = pa[NBK - 1];                // total bg count
    {
        const int grp = (tid & 256) | (255 - (tid & 255));
        const int excl = pa[tid] - cnt[grp];
        bsa[grp] = excl;
        cur[grp] = excl;
    }
    __syncthreads();

    // ---- counting-scatter keys into bucket groups ----
    #pragma unroll
    for (int t = 0; t < 8; ++t) {
        const int off = atomicAdd(&cur[(int)sgrp[t]], 1);
        gkeys[off] = skey[t];
    }
    __syncthreads();

    // ---- rank + output for this block's 256-proposal chunk ----
    if (tid < CHK) {
        const int p   = j * CHK + tid;
        const int idx = b * NP + p;
        u64 m = pm[idx];
        #pragma unroll
        for (int c = 1; c < NCH; ++c) {
            const u64 mc = pm[c * NBNP + idx];
            if (mc > m) m = mc;
        }
        const float best = __uint_as_float((unsigned)(m >> 16));
        const int   mi   = (NG - 1) - (int)(m & 0xFFFF);
        const int   cat  = (best >= 0.5f) ? 1 : 0;
        const float v    = pri[idx];
        int bkt = (int)(v * 256.0f); if (bkt > 255) bkt = 255;
        const int grp = cat * NBK + bkt;
        const u64 mine = ((u64)__float_as_uint(v) << 12) | (u64)(NP - 1 - p);

        const int gs = bsa[grp];
        const int gc = cnt[grp];
        int ahead = 0;
        for (int i = gs; i < gs + gc; ++i)
            ahead += (gkeys[i] > mine) ? 1 : 0;
        const int rank = (gs - (cat ? s_tot0 : 0)) + ahead;
        const int cap  = cat ? KFG : KBG;
        if (rank < cap) {
            const int slot = b * NS + (cat ? rank : KFG + rank);
            const float4 pb4 = prop[idx];
            const float4 tb4 = tgt[b * NG + mi];
            float4* orow = (float4*)(out + (size_t)slot * 8);
            orow[0] = pb4;
            orow[1] = tb4;
            out[OUT_BOX + slot] = cat ? (float)gtc[b * NG + mi] : (float)NCLS;
        }
    }
}

extern "C" void kernel_launch(void* const* d_in, const int* in_sizes, int n_in,
                              void* d_out, int out_size, void* d_ws, size_t ws_size,
                              hipStream_t stream) {
    const float4* prop = (const float4*)d_in[0];   // [16,4096,4] f32
    const float4* tgt  = (const float4*)d_in[1];   // [16,512,4]  f32
    const int*    gtc  = (const int*)  d_in[2];    // [16,512]    i32
    const float*  pri  = (const float*)d_in[3];    // [16,4096]   f32
    float* out = (float*)d_out;

    u64* pm = (u64*)d_ws;                          // NCH * NB*NP * 8B = 4 MiB

    k_match<<<NB * 16 * NCH, 256, 0, stream>>>(prop, tgt, pm, out);
    k_rank<<<NB * RBLK, 512, 0, stream>>>(prop, tgt, gtc, pri, pm, out);
}

// Round 7
// 45.375 us; speedup vs baseline: 4.3758x; 1.0331x over previous
//
#include <hip/hip_runtime.h>
#include <stdint.h>

#define NB 16        // images
#define NP 4096      // proposals/image
#define NG 512       // gt/image
#define NCH 8        // gt chunks for k_match
#define GC  (NG/NCH) // 64
#define NCLS 80
#define KFG 128
#define KBG 384
#define NS 512
#define OUT_BOX (NB*NS*8)   // 65536 floats
#define OUT_CLS (NB*NS)     // 8192 floats
#define NBNP (NB*NP)
#define NBK 256             // priority buckets per category
#define NGRP (2*NBK)        // 512 (cat,bucket) groups
#define RBLK 16             // rank blocks per image
#define CHK (NP/RBLK)       // 256 proposals ranked per block

typedef unsigned long long u64;

// ---------------------------------------------------------------------------
// Kernel 1: partial IoU max/argmax over a 64-gt chunk.  NO LDS: gt boxes are
// read at wave-uniform addresses (scalar-load path), areas recomputed inline.
// Division is UNCONDITIONAL and branchless (bit-exact vs reference; proven
// absmax=0.0 in R2).  Packed partial (iou_bits<<16 | (511-g)); u64 max across
// chunks == first-occurrence argmax.  grid = 2048 blocks x 256 thr.
// Also inits the output (boxes->0, cls->-1); harness poisons only once.
// ---------------------------------------------------------------------------
__global__ __launch_bounds__(256) void k_match(
    const float4* __restrict__ prop,
    const float4* __restrict__ tgt,
    u64* __restrict__ pm,              // [NCH][NB*NP]
    float* __restrict__ out)
{
    const int tid  = threadIdx.x;
    const int bx   = blockIdx.x;
    const int c    = bx & (NCH - 1);
    const int pblk = (bx >> 3) & 15;
    const int b    = bx >> 7;

    // ---- output init (524288 threads total) ----
    const int gid = bx * 256 + tid;
    if (gid < OUT_BOX) out[gid] = 0.0f;
    if (gid < OUT_CLS) out[OUT_BOX + gid] = -1.0f;

    const int p = pblk * 256 + tid;
    const float4 pb = prop[b * NP + p];
    const float ap = __fmul_rn(__fsub_rn(pb.z, pb.x), __fsub_rn(pb.w, pb.y));

    const float4* __restrict__ tg = tgt + b * NG + c * GC;

    float best = -1.0f;
    int   bi   = 0;
    #pragma unroll 8
    for (int g = 0; g < GC; ++g) {
        const float4 t = tg[g];                          // wave-uniform load
        const float at  = __fmul_rn(__fsub_rn(t.z, t.x), __fsub_rn(t.w, t.y));
        const float ltx = fmaxf(t.x, pb.x);
        const float lty = fmaxf(t.y, pb.y);
        const float rbx = fminf(t.z, pb.z);
        const float rby = fminf(t.w, pb.w);
        const float w = fmaxf(__fsub_rn(rbx, ltx), 0.0f);
        const float h = fmaxf(__fsub_rn(rby, lty), 0.0f);
        const float inter = __fmul_rn(w, h);
        const float uni   = __fsub_rn(__fadd_rn(at, ap), inter);
        // inter==0 -> +0.0/uni = +0.0 == reference's where-branch value
        const float iou   = __fdiv_rn(inter, fmaxf(uni, 1e-8f));
        if (iou > best) { best = iou; bi = g; }          // cndmask, first-occ
    }
    const int gg = c * GC + bi;
    pm[c * NBNP + b * NP + p] =
        ((u64)__float_as_uint(best) << 16) | (u64)(NG - 1 - gg);
}

// ---------------------------------------------------------------------------
// Kernel 1.5: fold the 8 partials once; emit packed meta
//   cmb = pribits<<18 | cat<<17 | bkt<<9 | mi      (50 bits)
// grid = 256 blocks x 256 thr (one thread per proposal).
// ---------------------------------------------------------------------------
__global__ __launch_bounds__(256) void k_combine(
    const float* __restrict__ pri,
    const u64*  __restrict__ pm,
    u64* __restrict__ pmc)             // [NB*NP]
{
    const int idx = blockIdx.x * 256 + threadIdx.x;
    u64 m = pm[idx];
    #pragma unroll
    for (int c = 1; c < NCH; ++c) {
        const u64 mc = pm[c * NBNP + idx];
        if (mc > m) m = mc;
    }
    const float best = __uint_as_float((unsigned)(m >> 16));
    const int   mi   = (NG - 1) - (int)(m & 0xFFFF);
    const int   cat  = (best >= 0.5f) ? 1 : 0;
    const float v    = pri[idx];
    int bkt = (int)(v * 256.0f); if (bkt > 255) bkt = 255;
    pmc[idx] = ((u64)__float_as_uint(v) << 18) | ((u64)cat << 17)
             | ((u64)bkt << 9) | (u64)mi;
}

// ---------------------------------------------------------------------------
// Kernel 2: exact stable rank via 256-bucket counting sort per category,
// redundantly staged per block (256 blocks = 1/CU).  Groups whose start
// offset is already past the category cap are skipped entirely (their
// members can't be selected).  rank = (group start - category base) +
// (# same-bucket keys strictly greater).  key = pribits<<12 | (4095-p).
// grid = NB*RBLK = 256 blocks x 512 thr.
// ---------------------------------------------------------------------------
__global__ __launch_bounds__(512) void k_rank(
    const float4* __restrict__ prop,
    const float4* __restrict__ tgt,
    const int*   __restrict__ gtc,
    const float* __restrict__ pri,
    const u64*   __restrict__ pmc,
    float* __restrict__ out)
{
    __shared__ u64 gkeys[NP];          // 32 KiB grouped keys
    __shared__ unsigned smeta[NP];     // 16 KiB (mi | bkt<<9 | cat<<17)
    __shared__ int cnt[NGRP];
    __shared__ int bsa[NGRP];
    __shared__ int cur[NGRP];
    __shared__ int sA[NGRP], sB[NGRP];
    __shared__ int s_tot0;

    const int tid = threadIdx.x;       // 0..511
    const int b   = blockIdx.x >> 4;
    const int j   = blockIdx.x & (RBLK - 1);

    cnt[tid] = 0;
    __syncthreads();

    // ---- stage: 8 proposals/thread, 1 load each ----
    u64 scmb[8];
    #pragma unroll
    for (int t = 0; t < 8; ++t) {
        const int p = tid + t * 512;
        const u64 cmb = pmc[b * NP + p];
        scmb[t] = cmb;
        smeta[p] = (unsigned)(cmb & 0x3FFFFu);
        atomicAdd(&cnt[(int)((cmb >> 9) & 0x1FF)], 1);   // grp = cat<<8 | bkt
    }
    __syncthreads();

    // ---- scan order s: bg first, buckets DESCENDING: grp(s)=(s&256)|(255-(s&255))
    sA[tid] = cnt[(tid & 256) | (255 - (tid & 255))];
    __syncthreads();

    int* pa = sA; int* pb2 = sB;
    for (int d = 1; d < NGRP; d <<= 1) {               // 9-step inclusive scan
        pb2[tid] = pa[tid] + ((tid >= d) ? pa[tid - d] : 0);
        __syncthreads();
        int* tmp = pa; pa = pb2; pb2 = tmp;
    }
    if (tid == 0) s_tot0 = pa[NBK - 1];                // total bg count
    {
        const int grp = (tid & 256) | (255 - (tid & 255));
        const int excl = pa[tid] - cnt[grp];
        bsa[grp] = excl;
        cur[grp] = excl;
    }
    __syncthreads();

    const int tot0 = s_tot0;

    // ---- scatter keys of groups that can still matter ----
    #pragma unroll
    for (int t = 0; t < 8; ++t) {
        const u64 cmb = scmb[t];
        const int grp = (int)((cmb >> 9) & 0x1FF);
        const int cat = (int)((cmb >> 17) & 1);
        const int gs  = bsa[grp];
        const int cap = cat ? KFG : KBG;
        if (gs - (cat ? tot0 : 0) < cap) {
            const int p = tid + t * 512;
            const u64 key = ((cmb >> 18) << 12) | (u64)(NP - 1 - p);
            const int off = atomicAdd(&cur[grp], 1);
            gkeys[off] = key;
        }
    }
    __syncthreads();

    // ---- rank + output for this block's 256-proposal chunk ----
    if (tid < CHK) {
        const int p   = j * CHK + tid;
        const int idx = b * NP + p;
        const unsigned meta = smeta[p];
        const int mi  = (int)(meta & 0x1FF);
        const int cat = (int)((meta >> 17) & 1);
        const int grp = (int)((meta >> 9) & 0x1FF);
        const int gs  = bsa[grp];
        const int catbase = cat ? tot0 : 0;
        const int cap = cat ? KFG : KBG;
        if (gs - catbase < cap) {
            const u64 mine = ((u64)__float_as_uint(pri[idx]) << 12)
                           | (u64)(NP - 1 - p);
            const int gc = cnt[grp];
            int ahead = 0;
            for (int i = gs; i < gs + gc; ++i)
                ahead += (gkeys[i] > mine) ? 1 : 0;
            const int rank = (gs - catbase) + ahead;
            if (rank < cap) {
                const int slot = b * NS + (cat ? rank : KFG + rank);
                const float4 pb4 = prop[idx];
                const float4 tb4 = tgt[b * NG + mi];
                float4* orow = (float4*)(out + (size_t)slot * 8);
                orow[0] = pb4;
                orow[1] = tb4;
                out[OUT_BOX + slot] = cat ? (float)gtc[b * NG + mi]
                                          : (float)NCLS;
            }
        }
    }
}

extern "C" void kernel_launch(void* const* d_in, const int* in_sizes, int n_in,
                              void* d_out, int out_size, void* d_ws, size_t ws_size,
                              hipStream_t stream) {
    const float4* prop = (const float4*)d_in[0];   // [16,4096,4] f32
    const float4* tgt  = (const float4*)d_in[1];   // [16,512,4]  f32
    const int*    gtc  = (const int*)  d_in[2];    // [16,512]    i32
    const float*  pri  = (const float*)d_in[3];    // [16,4096]   f32
    float* out = (float*)d_out;

    u64* pm  = (u64*)d_ws;                                    // 4 MiB
    u64* pmc = (u64*)((char*)d_ws + (size_t)NCH * NBNP * 8);  // 512 KiB

    k_match<<<NB * 16 * NCH, 256, 0, stream>>>(prop, tgt, pm, out);
    k_combine<<<NBNP / 256, 256, 0, stream>>>(pri, pm, pmc);
    k_rank<<<NB * RBLK, 512, 0, stream>>>(prop, tgt, gtc, pri, pmc, out);
}

// Round 8
// 44.402 us; speedup vs baseline: 4.4717x; 1.0219x over previous
//
#include <hip/hip_runtime.h>
#include <stdint.h>

#define NB 16        // images
#define NP 4096      // proposals/image
#define NG 512       // gt/image
#define NCH 8        // gt chunks for k_match
#define GC  (NG/NCH) // 64
#define NCLS 80
#define KFG 128
#define KBG 384
#define NS 512
#define OUT_BOX (NB*NS*8)   // 65536 floats
#define OUT_CLS (NB*NS)     // 8192 floats
#define NBNP (NB*NP)
#define NBK 256             // priority buckets per category
#define NGRP (2*NBK)        // 512 (cat,bucket) groups
#define RBLK 16             // rank blocks per image
#define CHK (NP/RBLK)       // 256 proposals ranked per block

typedef unsigned long long u64;

// ---------------------------------------------------------------------------
// Kernel 1: partial IoU argmax over a 64-gt chunk WITHOUT per-pair division.
// Running best tracked as a fraction (bA,bB); challenger (inter,uni) compared
// via exact cross-products (2Prod-FMA: p+e == a*b exactly):
//   dd = (p1-p2) + (e1-e2),  p1=inter*bB, p2=bA*uni.
// dd>thr  -> exact ratio strictly greater -> update (RN-monotone => safe).
// |dd|<=thr (thr = 2^-20 * max(p1,p2), 8x margin over the 1-ulp RN-tie zone)
//   -> possible RN tie (reference keeps FIRST index) -> flag lane, recompute
//      the whole chunk with reference divisions in a rare divergent tail.
// Exact ties (d==0 && e1==e2, incl. the common 0 vs 0 case) keep-first in
// both schemes -> excluded from flagging.  Unflagged lanes do ONE division
// for the RN value.  Cross-chunk RN ties resolved exactly by packed-u64 max
// (iou_bits<<16 | (511-g)).  grid = 2048 blocks x 256 thr.
// Also inits the output (boxes->0, cls->-1); harness poisons only once.
// ---------------------------------------------------------------------------
__global__ __launch_bounds__(256) void k_match(
    const float4* __restrict__ prop,
    const float4* __restrict__ tgt,
    u64* __restrict__ pm,              // [NCH][NB*NP]
    float* __restrict__ out)
{
    const int tid  = threadIdx.x;
    const int bx   = blockIdx.x;
    const int c    = bx & (NCH - 1);
    const int pblk = (bx >> 3) & 15;
    const int b    = bx >> 7;

    // ---- output init (524288 threads total) ----
    const int gid = bx * 256 + tid;
    if (gid < OUT_BOX) out[gid] = 0.0f;
    if (gid < OUT_CLS) out[OUT_BOX + gid] = -1.0f;

    const int p = pblk * 256 + tid;
    const float4 pb = prop[b * NP + p];
    const float ap = __fmul_rn(__fsub_rn(pb.z, pb.x), __fsub_rn(pb.w, pb.y));

    const float4* __restrict__ tg = tgt + b * NG + c * GC;

    float bA = -1.0f, bB = 1.0f;       // running best as fraction bA/bB
    int   bi  = 0;
    bool  amb = false;
    #pragma unroll 8
    for (int g = 0; g < GC; ++g) {
        const float4 t = tg[g];                          // wave-uniform load
        const float at  = __fmul_rn(__fsub_rn(t.z, t.x), __fsub_rn(t.w, t.y));
        const float ltx = fmaxf(t.x, pb.x);
        const float lty = fmaxf(t.y, pb.y);
        const float rbx = fminf(t.z, pb.z);
        const float rby = fminf(t.w, pb.w);
        const float w = fmaxf(__fsub_rn(rbx, ltx), 0.0f);
        const float h = fmaxf(__fsub_rn(rby, lty), 0.0f);
        const float inter = __fmul_rn(w, h);
        const float uni   = __fsub_rn(__fadd_rn(at, ap), inter);

        const float p1 = __fmul_rn(inter, bB);
        const float e1 = fmaf(inter, bB, -p1);           // exact: inter*bB = p1+e1
        const float p2 = __fmul_rn(bA, uni);
        const float e2 = fmaf(bA, uni, -p2);             // exact: bA*uni = p2+e2
        const float d  = __fsub_rn(p1, p2);
        const float dd = __fadd_rn(d, __fsub_rn(e1, e2));
        const float thr = __fmul_rn(fmaxf(p1, p2), 0x1p-20f);

        const bool exact_tie = (d == 0.0f) & (e1 == e2);
        amb = amb | ((__builtin_fabsf(dd) <= thr) & !exact_tie);
        if (dd > thr) { bA = inter; bB = uni; bi = g; }  // first-occurrence
    }

    float best;
    if (amb) {
        // rare exact fallback: reference semantics (RN division per pair)
        best = -1.0f; bi = 0;
        for (int g = 0; g < GC; ++g) {
            const float4 t = tg[g];
            const float at  = __fmul_rn(__fsub_rn(t.z, t.x), __fsub_rn(t.w, t.y));
            const float ltx = fmaxf(t.x, pb.x);
            const float lty = fmaxf(t.y, pb.y);
            const float rbx = fminf(t.z, pb.z);
            const float rby = fminf(t.w, pb.w);
            const float w = fmaxf(__fsub_rn(rbx, ltx), 0.0f);
            const float h = fmaxf(__fsub_rn(rby, lty), 0.0f);
            const float inter = __fmul_rn(w, h);
            const float uni   = __fsub_rn(__fadd_rn(at, ap), inter);
            const float iou   = __fdiv_rn(inter, fmaxf(uni, 1e-8f));
            if (iou > best) { best = iou; bi = g; }
        }
    } else {
        // winner's RN value; bA>=0 after g=0 (g=0 always decisively updates)
        best = __fdiv_rn(bA, fmaxf(bB, 1e-8f));
    }

    const int gg = c * GC + bi;
    pm[c * NBNP + b * NP + p] =
        ((u64)__float_as_uint(best) << 16) | (u64)(NG - 1 - gg);
}

// ---------------------------------------------------------------------------
// Kernel 1.5: fold the 8 partials once; emit packed meta
//   cmb = pribits<<18 | cat<<17 | bkt<<9 | mi      (50 bits)
// grid = 256 blocks x 256 thr (one thread per proposal).
// ---------------------------------------------------------------------------
__global__ __launch_bounds__(256) void k_combine(
    const float* __restrict__ pri,
    const u64*  __restrict__ pm,
    u64* __restrict__ pmc)             // [NB*NP]
{
    const int idx = blockIdx.x * 256 + threadIdx.x;
    u64 m = pm[idx];
    #pragma unroll
    for (int c = 1; c < NCH; ++c) {
        const u64 mc = pm[c * NBNP + idx];
        if (mc > m) m = mc;
    }
    const float best = __uint_as_float((unsigned)(m >> 16));
    const int   mi   = (NG - 1) - (int)(m & 0xFFFF);
    const int   cat  = (best >= 0.5f) ? 1 : 0;
    const float v    = pri[idx];
    int bkt = (int)(v * 256.0f); if (bkt > 255) bkt = 255;
    pmc[idx] = ((u64)__float_as_uint(v) << 18) | ((u64)cat << 17)
             | ((u64)bkt << 9) | (u64)mi;
}

// ---------------------------------------------------------------------------
// Kernel 2: exact stable rank via 256-bucket counting sort per category,
// redundantly staged per block (256 blocks = 1/CU).  Groups whose start
// offset is already past the category cap are skipped entirely (their
// members can't be selected).  rank = (group start - category base) +
// (# same-bucket keys strictly greater).  key = pribits<<12 | (4095-p).
// grid = NB*RBLK = 256 blocks x 512 thr.
// ---------------------------------------------------------------------------
__global__ __launch_bounds__(512) void k_rank(
    const float4* __restrict__ prop,
    const float4* __restrict__ tgt,
    const int*   __restrict__ gtc,
    const float* __restrict__ pri,
    const u64*   __restrict__ pmc,
    float* __restrict__ out)
{
    __shared__ u64 gkeys[NP];          // 32 KiB grouped keys
    __shared__ unsigned smeta[NP];     // 16 KiB (mi | bkt<<9 | cat<<17)
    __shared__ int cnt[NGRP];
    __shared__ int bsa[NGRP];
    __shared__ int cur[NGRP];
    __shared__ int sA[NGRP], sB[NGRP];
    __shared__ int s_tot0;

    const int tid = threadIdx.x;       // 0..511
    const int b   = blockIdx.x >> 4;
    const int j   = blockIdx.x & (RBLK - 1);

    cnt[tid] = 0;
    __syncthreads();

    // ---- stage: 8 proposals/thread, 1 load each ----
    u64 scmb[8];
    #pragma unroll
    for (int t = 0; t < 8; ++t) {
        const int p = tid + t * 512;
        const u64 cmb = pmc[b * NP + p];
        scmb[t] = cmb;
        smeta[p] = (unsigned)(cmb & 0x3FFFFu);
        atomicAdd(&cnt[(int)((cmb >> 9) & 0x1FF)], 1);   // grp = cat<<8 | bkt
    }
    __syncthreads();

    // ---- scan order s: bg first, buckets DESCENDING: grp(s)=(s&256)|(255-(s&255))
    sA[tid] = cnt[(tid & 256) | (255 - (tid & 255))];
    __syncthreads();

    int* pa = sA; int* pb2 = sB;
    for (int d = 1; d < NGRP; d <<= 1) {               // 9-step inclusive scan
        pb2[tid] = pa[tid] + ((tid >= d) ? pa[tid - d] : 0);
        __syncthreads();
        int* tmp = pa; pa = pb2; pb2 = tmp;
    }
    if (tid == 0) s_tot0 = pa[NBK - 1];                // total bg count
    {
        const int grp = (tid & 256) | (255 - (tid & 255));
        const int excl = pa[tid] - cnt[grp];
        bsa[grp] = excl;
        cur[grp] = excl;
    }
    __syncthreads();

    const int tot0 = s_tot0;

    // ---- scatter keys of groups that can still matter ----
    #pragma unroll
    for (int t = 0; t < 8; ++t) {
        const u64 cmb = scmb[t];
        const int grp = (int)((cmb >> 9) & 0x1FF);
        const int cat = (int)((cmb >> 17) & 1);
        const int gs  = bsa[grp];
        const int cap = cat ? KFG : KBG;
        if (gs - (cat ? tot0 : 0) < cap) {
            const int p = tid + t * 512;
            const u64 key = ((cmb >> 18) << 12) | (u64)(NP - 1 - p);
            const int off = atomicAdd(&cur[grp], 1);
            gkeys[off] = key;
        }
    }
    __syncthreads();

    // ---- rank + output for this block's 256-proposal chunk ----
    if (tid < CHK) {
        const int p   = j * CHK + tid;
        const int idx = b * NP + p;
        const unsigned meta = smeta[p];
        const int mi  = (int)(meta & 0x1FF);
        const int cat = (int)((meta >> 17) & 1);
        const int grp = (int)((meta >> 9) & 0x1FF);
        const int gs  = bsa[grp];
        const int catbase = cat ? tot0 : 0;
        const int cap = cat ? KFG : KBG;
        if (gs - catbase < cap) {
            const u64 mine = ((u64)__float_as_uint(pri[idx]) << 12)
                           | (u64)(NP - 1 - p);
            const int gc = cnt[grp];
            int ahead = 0;
            for (int i = gs; i < gs + gc; ++i)
                ahead += (gkeys[i] > mine) ? 1 : 0;
            const int rank = (gs - catbase) + ahead;
            if (rank < cap) {
                const int slot = b * NS + (cat ? rank : KFG + rank);
                const float4 pb4 = prop[idx];
                const float4 tb4 = tgt[b * NG + mi];
                float4* orow = (float4*)(out + (size_t)slot * 8);
                orow[0] = pb4;
                orow[1] = tb4;
                out[OUT_BOX + slot] = cat ? (float)gtc[b * NG + mi]
                                          : (float)NCLS;
            }
        }
    }
}

extern "C" void kernel_launch(void* const* d_in, const int* in_sizes, int n_in,
                              void* d_out, int out_size, void* d_ws, size_t ws_size,
                              hipStream_t stream) {
    const float4* prop = (const float4*)d_in[0];   // [16,4096,4] f32
    const float4* tgt  = (const float4*)d_in[1];   // [16,512,4]  f32
    const int*    gtc  = (const int*)  d_in[2];    // [16,512]    i32
    const float*  pri  = (const float*)d_in[3];    // [16,4096]   f32
    float* out = (float*)d_out;

    u64* pm  = (u64*)d_ws;                                    // 4 MiB
    u64* pmc = (u64*)((char*)d_ws + (size_t)NCH * NBNP * 8);  // 512 KiB

    k_match<<<NB * 16 * NCH, 256, 0, stream>>>(prop, tgt, pm, out);
    k_combine<<<NBNP / 256, 256, 0, stream>>>(pri, pm, pmc);
    k_rank<<<NB * RBLK, 512, 0, stream>>>(prop, tgt, gtc, pri, pmc, out);
}